// Round 1
// baseline (20116.528 us; speedup 1.0000x reference)
//
#include <hip/hip_runtime.h>
#include <cstdint>

// SpikingConv2DLayer fused forward for MI355X (gfx950), fp32 exact-path.
//
// Shapes: x[32][8][256][128], w[64][8][5][5], b[64], beta[1], sigma[1] (unused fwd)
// out: spk [32][64][256][128] f32 (+ loss, + spk_spread appended) = 67108866 floats.
//
// Key algebraic facts used:
//  * prev never decays -> each neuron fires at most once, spike value is exactly 3.0
//  * rst couples channels only at fixed (b,w) -> 64-bit fire mask per column
//  * loss = 0.5*mean(spk^2) = 4.5*total_fires/2^26 (exact in fp32)
//  * spk_spread = 3*max_t fires_t / 2^18 (exact)
//
// Workspace layout (needs >= 17664 bytes):
//  ws[0..4095]    : D3 = 3 * (w_flat @ w_flat^T)   (64x64 f32)
//  ws[4096..4159] : inv_norm[64] = 1/(||w_o||^2 + 1e-8)
//  ws[4160..]     : gfires[256] u32 (per-t global fire counts)

#define NB 32
#define NC 8
#define NT 256
#define NW 128
#define NO 64
#define WT 16
#define WPITCH 324  // floats per cout row in LDS; 324*4B=1296B (16B aligned), co*324 % 32 = co*4 -> <=2-way bank conflict

__global__ __launch_bounds__(1024)
void prep_kernel(const float* __restrict__ w, float* __restrict__ d3,
                 float* __restrict__ invn, unsigned int* __restrict__ gfires)
{
    __shared__ float wsh[NO * 200];
    const int tid = threadIdx.x;
    for (int i = tid; i < NO * 200; i += 1024) wsh[i] = w[i];
    if (tid < NT) gfires[tid] = 0u;
    __syncthreads();
#pragma unroll
    for (int p = 0; p < 4; ++p) {
        int idx = p * 1024 + tid;            // 4096 (o,e) pairs
        int o = idx >> 6, e = idx & 63;
        float acc = 0.0f;
        for (int i = 0; i < 200; i += 4) {
            float4 av = *(const float4*)&wsh[o * 200 + i];
            float4 bv = *(const float4*)&wsh[e * 200 + i];
            acc += av.x * bv.x + av.y * bv.y + av.z * bv.z + av.w * bv.w;
        }
        d3[idx] = 3.0f * acc;
        if (o == e) invn[o] = 1.0f / (acc + 1e-8f);
    }
}

__global__ __launch_bounds__(256, 1)
void spk_kernel(const float* __restrict__ x, const float* __restrict__ wglob,
                const float* __restrict__ bias, const float* __restrict__ beta_p,
                const float* __restrict__ d3g, const float* __restrict__ invng,
                float* __restrict__ out, unsigned int* __restrict__ gfires)
{
    __shared__ float wsm[NO * WPITCH];            // 82944 B, padded 5->8 per (c,kt) group
    __shared__ float d3s[NO * NO];                // 16384 B
    __shared__ float xsh[NC][5][20];              // 3200 B ring buffer of x rows
    __shared__ unsigned long long smask[2][WT];   // per-column fire masks (prev step / cur step)
    __shared__ unsigned int sfires[NT];           // per-t fire counts (this block)
    __shared__ unsigned int scnt[2];              // total fires last/cur step (skip-rst fast path)

    const int tid = threadIdx.x;
    const int bb = blockIdx.x >> 3;
    const int w0 = (blockIdx.x & 7) * WT;
    const int co = tid >> 2;
    const int wq = tid & 3;
    const int wb = wq * 4;           // local column base (0,4,8,12)

    // --- staging lane mapping (threads 0..159 stage one x element per row) ---
    const int sc  = (tid < 160) ? (tid / 20) : 0;
    const int slw = (tid < 160) ? (tid % 20) : 0;
    const int sgw = w0 + slw - 2;
    const bool svalid = (tid < 160) && (sgw >= 0) && (sgw < NW);
    const float* xrowbase = x + (size_t)((bb * NC + sc) * NT) * NW + sgw;

    // prefetch row 2 into register (rows 0,1 staged directly below)
    float preg = svalid ? xrowbase[2 * NW] : 0.0f;

    // --- load weights into padded LDS ---
    for (int i = tid; i < NO * 200; i += 256) {
        int oi = i / 200; int r = i - oi * 200; int g = r / 5; int kw = r - g * 5;
        wsm[oi * WPITCH + g * 8 + kw] = wglob[i];
    }
    for (int i = tid; i < NO * NO; i += 256) d3s[i] = d3g[i];
    if (tid < 160) {
        xsh[sc][0][slw] = svalid ? xrowbase[0]  : 0.0f;   // row 0
        xsh[sc][1][slw] = svalid ? xrowbase[NW] : 0.0f;   // row 1
        xsh[sc][3][slw] = 0.0f;                           // row -2
        xsh[sc][4][slw] = 0.0f;                           // row -1
    }
    if (tid < WT) { smask[0][tid] = 0ull; smask[1][tid] = 0ull; }
    if (tid < 2) scnt[tid] = 0u;
    sfires[tid] = 0u;

    const float invn = invng[co];
    const float bco  = bias[co];
    const float beta = beta_p[0];
    const float omb  = 1.0f - beta;

    float mem0 = 0.f, mem1 = 0.f, mem2 = 0.f, mem3 = 0.f;
    unsigned int fired = 0u;

    __syncthreads();

    for (int t = 0; t < NT; ++t) {
        // ---- phase 1: commit prefetched row t+2, issue prefetch of row t+3 ----
        if (tid < 160) {
            xsh[sc][(t + 2) % 5][slw] = preg;
            int nr = t + 3;
            preg = (svalid && nr < NT) ? xrowbase[(size_t)nr * NW] : 0.0f;
        }
        if (tid < WT) smask[(t + 1) & 1][tid] = 0ull;
        if (tid == 160) scnt[(t + 1) & 1] = 0u;
        __syncthreads();

        // ---- phase 2: conv + scan update ----
        float a0 = 0.f, a1 = 0.f, a2 = 0.f, a3 = 0.f;
        int sl[5];
#pragma unroll
        for (int kt = 0; kt < 5; ++kt) sl[kt] = (t + 3 + kt) % 5;  // slot of row t-2+kt
#pragma unroll
        for (int c = 0; c < NC; ++c) {
#pragma unroll
            for (int kt = 0; kt < 5; ++kt) {
                const float* xp = &xsh[c][sl[kt]][wb];
                float4 xa = *(const float4*)xp;
                float4 xb = *(const float4*)(xp + 4);
                const float* wp = &wsm[co * WPITCH + (c * 5 + kt) * 8];
                float4 wv = *(const float4*)wp;
                float w4 = wp[4];
                a0 += wv.x * xa.x + wv.y * xa.y + wv.z * xa.z + wv.w * xa.w + w4 * xb.x;
                a1 += wv.x * xa.y + wv.y * xa.z + wv.z * xa.w + wv.w * xb.x + w4 * xb.y;
                a2 += wv.x * xa.z + wv.y * xa.w + wv.z * xb.x + wv.w * xb.y + w4 * xb.z;
                a3 += wv.x * xa.w + wv.y * xb.x + wv.z * xb.y + wv.w * xb.z + w4 * xb.w;
            }
        }

        // rst from previous-step fire masks (sparse; usually skipped entirely)
        float r0 = 0.f, r1 = 0.f, r2 = 0.f, r3 = 0.f;
        if (scnt[t & 1] != 0u) {
            unsigned long long m0 = smask[t & 1][wb + 0];
            unsigned long long m1 = smask[t & 1][wb + 1];
            unsigned long long m2 = smask[t & 1][wb + 2];
            unsigned long long m3 = smask[t & 1][wb + 3];
            while (m0) { int c = __builtin_ctzll(m0); m0 &= m0 - 1; r0 += d3s[c * NO + co]; }
            while (m1) { int c = __builtin_ctzll(m1); m1 &= m1 - 1; r1 += d3s[c * NO + co]; }
            while (m2) { int c = __builtin_ctzll(m2); m2 &= m2 - 1; r2 += d3s[c * NO + co]; }
            while (m3) { int c = __builtin_ctzll(m3); m3 &= m3 - 1; r3 += d3s[c * NO + co]; }
        }

        mem0 = (mem0 - r0) * beta + a0 * omb;
        mem1 = (mem1 - r1) * beta + a1 * omb;
        mem2 = (mem2 - r2) * beta + a2 * omb;
        mem3 = (mem3 - r3) * beta + a3 * omb;

        float s0 = 0.f, s1 = 0.f, s2 = 0.f, s3 = 0.f;
        if (!(fired & 1u) && (mem0 * invn - bco > 0.0f)) {
            s0 = 3.0f; fired |= 1u;
            atomicOr(&smask[(t + 1) & 1][wb + 0], 1ull << co);
            atomicAdd(&sfires[t], 1u); atomicAdd(&scnt[(t + 1) & 1], 1u);
        }
        if (!(fired & 2u) && (mem1 * invn - bco > 0.0f)) {
            s1 = 3.0f; fired |= 2u;
            atomicOr(&smask[(t + 1) & 1][wb + 1], 1ull << co);
            atomicAdd(&sfires[t], 1u); atomicAdd(&scnt[(t + 1) & 1], 1u);
        }
        if (!(fired & 4u) && (mem2 * invn - bco > 0.0f)) {
            s2 = 3.0f; fired |= 4u;
            atomicOr(&smask[(t + 1) & 1][wb + 2], 1ull << co);
            atomicAdd(&sfires[t], 1u); atomicAdd(&scnt[(t + 1) & 1], 1u);
        }
        if (!(fired & 8u) && (mem3 * invn - bco > 0.0f)) {
            s3 = 3.0f; fired |= 8u;
            atomicOr(&smask[(t + 1) & 1][wb + 3], 1ull << co);
            atomicAdd(&sfires[t], 1u); atomicAdd(&scnt[(t + 1) & 1], 1u);
        }

        float4 sv = make_float4(s0, s1, s2, s3);
        *(float4*)(out + ((size_t)((bb * NO + co) * NT + t) * NW + w0 + wb)) = sv;

        __syncthreads();
    }

    // accumulate this block's per-t fire counts into global
    atomicAdd(&gfires[tid], sfires[tid]);
}

__global__ __launch_bounds__(256)
void fin_kernel(const unsigned int* __restrict__ gfires, float* __restrict__ out)
{
    const int tid = threadIdx.x;
    unsigned int v = gfires[tid];
    unsigned int s = v, m = v;
    for (int off = 32; off > 0; off >>= 1) {
        s += __shfl_down(s, off);
        unsigned int o = __shfl_down(m, off);
        m = m > o ? m : o;
    }
    __shared__ unsigned int ls[4], lm[4];
    if ((tid & 63) == 0) { ls[tid >> 6] = s; lm[tid >> 6] = m; }
    __syncthreads();
    if (tid == 0) {
        unsigned int ts = 0, tm = 0;
        for (int i = 0; i < 4; ++i) { ts += ls[i]; tm = tm > lm[i] ? tm : lm[i]; }
        // loss = 0.5 * mean(spk^2) = 0.5 * 9 * F / 67108864
        out[67108864] = 4.5f * (float)ts / 67108864.0f;
        // spread = 3 * max_t fires_t / (32*64*128)
        out[67108865] = 3.0f * (float)tm / 262144.0f;
    }
}

extern "C" void kernel_launch(void* const* d_in, const int* in_sizes, int n_in,
                              void* d_out, int out_size, void* d_ws, size_t ws_size,
                              hipStream_t stream)
{
    const float* x    = (const float*)d_in[0];
    const float* w    = (const float*)d_in[1];
    const float* b    = (const float*)d_in[2];
    const float* beta = (const float*)d_in[3];
    // d_in[4] = sigma: unused in forward

    float* out  = (float*)d_out;
    float* wsf  = (float*)d_ws;
    float* d3   = wsf;                               // 4096 floats
    float* invn = wsf + 4096;                        // 64 floats
    unsigned int* gf = (unsigned int*)(wsf + 4160);  // 256 u32

    prep_kernel<<<1, 1024, 0, stream>>>(w, d3, invn, gf);
    spk_kernel<<<256, 256, 0, stream>>>(x, w, b, beta, d3, invn, out, gf);
    fin_kernel<<<1, 256, 0, stream>>>(gf, out);
}

// Round 3
// 823.274 us; speedup vs baseline: 24.4348x; 24.4348x over previous
//
#include <hip/hip_runtime.h>
#include <cstdint>

// SpikingConv2DLayer fused forward for MI355X (gfx950), fp32 exact-path. v2
// (resubmit — round 2 was an infra failure, no counters returned).
//
// Round-1 post-mortem: fully-unrolled per-step conv caused the compiler to
// batch ~520 floats of LDS-read results -> VGPR cap (256) -> scratch spill of
// ~4.2 KB/thread/step -> 69 GB of HBM spill traffic (matches FETCH+WRITE
// counters exactly). v2 restructures: t-chunks of 8, x rows cached in
// registers per input channel (272 ds_read_b128/chunk vs 960), c-loop kept
// rolled (#pragma unroll 1) so each scheduling region holds ~200 VGPRs.
//
// Exact-math facts reused from v1 (absmax was 0.0):
//  * prev never decays -> each neuron fires at most once, spike value 3.0
//  * rst couples channels only at fixed (b,w) -> 64-bit fire mask per column
//  * loss = 4.5*total_fires/2^26 ; spk_spread = 3*max_t fires_t/2^18

#define NB 32
#define NC 8
#define NT 256
#define NW 128
#define NO 64
#define WT 16
#define TC 8
#define NROWS 12            // TC + 4 halo rows
#define NCHUNK (NT / TC)
#define WPITCH 324          // 324*4B = 16B-aligned rows; co*324 % 32 = co*4 -> <=2-way bank alias (free)

__global__ __launch_bounds__(1024)
void prep_kernel(const float* __restrict__ w, float* __restrict__ d3,
                 float* __restrict__ invn, unsigned int* __restrict__ gfires)
{
    __shared__ float wsh[NO * 200];
    const int tid = threadIdx.x;
    for (int i = tid; i < NO * 200; i += 1024) wsh[i] = w[i];
    if (tid < NT) gfires[tid] = 0u;
    __syncthreads();
#pragma unroll
    for (int p = 0; p < 4; ++p) {
        int idx = p * 1024 + tid;            // 4096 (o,e) pairs
        int o = idx >> 6, e = idx & 63;
        float acc = 0.0f;
        for (int i = 0; i < 200; i += 4) {
            float4 av = *(const float4*)&wsh[o * 200 + i];
            float4 bv = *(const float4*)&wsh[e * 200 + i];
            acc += av.x * bv.x + av.y * bv.y + av.z * bv.z + av.w * bv.w;
        }
        d3[idx] = 3.0f * acc;
        if (o == e) invn[o] = 1.0f / (acc + 1e-8f);
    }
}

__global__ __launch_bounds__(256, 1)
void spk_kernel(const float* __restrict__ x, const float* __restrict__ wglob,
                const float* __restrict__ bias, const float* __restrict__ beta_p,
                const float* __restrict__ d3g, const float* __restrict__ invng,
                float* __restrict__ out, unsigned int* __restrict__ gfires)
{
    __shared__ float wsm[NO * WPITCH];            // 82944 B, (c,kt) groups padded 5->8
    __shared__ float d3s[NO * NO];                // 16384 B
    __shared__ float xsh[NC][NROWS][20];          // 7680 B  (row-major flat 1920 floats)
    __shared__ unsigned long long smask[3][WT];   // triple-buffered per-column fire masks
    __shared__ unsigned int scnt[3];              // fires per buffered step (skip-rst fast path)
    __shared__ unsigned int sfires[NT];           // per-t fire counts (this block)

    const int tid = threadIdx.x;
    const int bb  = blockIdx.x >> 3;
    const int w0  = (blockIdx.x & 7) * WT;
    const int co  = tid >> 2;
    const int wq4 = (tid & 3) * 4;                // local column base (0,4,8,12)

    // ---- init: weights (padded layout), D3, masks, chunk-0 x tile ----
    for (int i = tid; i < NO * 200; i += 256) {
        int oi = i / 200; int r = i - oi * 200; int g = r / 5; int kw = r - g * 5;
        wsm[oi * WPITCH + g * 8 + kw] = wglob[i];
    }
    for (int i = tid; i < NO * NO; i += 256) d3s[i] = d3g[i];
    if (tid < WT) { smask[0][tid] = 0ull; smask[1][tid] = 0ull; smask[2][tid] = 0ull; }
    if (tid < 3) scnt[tid] = 0u;
    sfires[tid] = 0u;

    const size_t xbbase = (size_t)bb * NC * NT * NW;
#pragma unroll
    for (int k = 0; k < 8; ++k) {                 // stage chunk 0 (rows -2..9)
        int i = tid + k * 256;
        if (i < NC * NROWS * 20) {
            int c = i / (NROWS * 20); int rem = i - c * (NROWS * 20);
            int row = rem / 20; int col = rem - row * 20;
            int tg = row - 2; int wg = w0 + col - 2;
            float v = 0.0f;
            if (tg >= 0 && tg < NT && wg >= 0 && wg < NW)
                v = x[xbbase + ((size_t)c * NT + tg) * NW + wg];
            ((float*)xsh)[i] = v;
        }
    }

    const float invn = invng[co];
    const float bco  = bias[co];
    const float beta = beta_p[0];
    const float omb  = 1.0f - beta;

    float mem0 = 0.f, mem1 = 0.f, mem2 = 0.f, mem3 = 0.f;
    unsigned int fired = 0u;

    __syncthreads();

#pragma unroll 1
    for (int ch = 0; ch < NCHUNK; ++ch) {
        const int tbase = ch * TC;

        // ---- prefetch next chunk's x tile into registers (T14: hide under conv) ----
        float sreg[8];
        if (ch + 1 < NCHUNK) {
#pragma unroll
            for (int k = 0; k < 8; ++k) {
                int i = tid + k * 256;
                sreg[k] = 0.0f;
                if (i < NC * NROWS * 20) {
                    int c = i / (NROWS * 20); int rem = i - c * (NROWS * 20);
                    int row = rem / 20; int col = rem - row * 20;
                    int tg = tbase + TC - 2 + row; int wg = w0 + col - 2;
                    if (tg >= 0 && tg < NT && wg >= 0 && wg < NW)
                        sreg[k] = x[xbbase + ((size_t)c * NT + tg) * NW + wg];
                }
            }
        }

        // ---- conv for this chunk: acc[t][j], x rows register-cached per c ----
        float acc[TC][4];
#pragma unroll
        for (int t = 0; t < TC; ++t) { acc[t][0] = acc[t][1] = acc[t][2] = acc[t][3] = 0.f; }

#pragma unroll 1
        for (int c = 0; c < NC; ++c) {
            float4 xr[NROWS][2];
#pragma unroll
            for (int r = 0; r < NROWS; ++r) {
                const float4* p = (const float4*)&xsh[c][r][wq4];
                xr[r][0] = p[0];
                xr[r][1] = p[1];
            }
            float4 wv0[5], wv1[5];
#pragma unroll
            for (int kt = 0; kt < 5; ++kt) {
                const float4* p = (const float4*)&wsm[co * WPITCH + (c * 5 + kt) * 8];
                wv0[kt] = p[0]; wv1[kt] = p[1];
            }
#pragma unroll
            for (int kt = 0; kt < 5; ++kt) {
                float4 wv = wv0[kt]; float w4 = wv1[kt].x;
#pragma unroll
                for (int t = 0; t < TC; ++t) {
                    float4 xa = xr[t + kt][0];
                    float4 xb = xr[t + kt][1];
                    acc[t][0] += wv.x * xa.x + wv.y * xa.y + wv.z * xa.z + wv.w * xa.w + w4 * xb.x;
                    acc[t][1] += wv.x * xa.y + wv.y * xa.z + wv.z * xa.w + wv.w * xb.x + w4 * xb.y;
                    acc[t][2] += wv.x * xa.z + wv.y * xa.w + wv.z * xb.x + wv.w * xb.y + w4 * xb.z;
                    acc[t][3] += wv.x * xa.w + wv.y * xb.x + wv.z * xb.y + wv.w * xb.z + w4 * xb.w;
                }
            }
        }

        // ---- scan: 8 sequential steps on register conv values ----
#pragma unroll
        for (int tt = 0; tt < TC; ++tt) {
            const int t = tbase + tt;
            const int cur = t % 3, nxt = (t + 1) % 3, clr = (t + 2) % 3;

            if (tid < WT) smask[clr][tid] = 0ull;     // buffer for step t+2 (idle this step)
            if (tid == 0) scnt[clr] = 0u;

            float r0 = 0.f, r1 = 0.f, r2 = 0.f, r3 = 0.f;
            if (scnt[cur] != 0u) {
                unsigned long long m0 = smask[cur][wq4 + 0];
                unsigned long long m1 = smask[cur][wq4 + 1];
                unsigned long long m2 = smask[cur][wq4 + 2];
                unsigned long long m3 = smask[cur][wq4 + 3];
                while (m0) { int c = __builtin_ctzll(m0); m0 &= m0 - 1; r0 += d3s[c * NO + co]; }
                while (m1) { int c = __builtin_ctzll(m1); m1 &= m1 - 1; r1 += d3s[c * NO + co]; }
                while (m2) { int c = __builtin_ctzll(m2); m2 &= m2 - 1; r2 += d3s[c * NO + co]; }
                while (m3) { int c = __builtin_ctzll(m3); m3 &= m3 - 1; r3 += d3s[c * NO + co]; }
            }

            mem0 = (mem0 - r0) * beta + acc[tt][0] * omb;
            mem1 = (mem1 - r1) * beta + acc[tt][1] * omb;
            mem2 = (mem2 - r2) * beta + acc[tt][2] * omb;
            mem3 = (mem3 - r3) * beta + acc[tt][3] * omb;

            float s0 = 0.f, s1 = 0.f, s2 = 0.f, s3 = 0.f;
            if (!(fired & 1u) && (mem0 * invn - bco > 0.0f)) {
                s0 = 3.0f; fired |= 1u;
                atomicOr(&smask[nxt][wq4 + 0], 1ull << co);
                atomicAdd(&sfires[t], 1u); atomicAdd(&scnt[nxt], 1u);
            }
            if (!(fired & 2u) && (mem1 * invn - bco > 0.0f)) {
                s1 = 3.0f; fired |= 2u;
                atomicOr(&smask[nxt][wq4 + 1], 1ull << co);
                atomicAdd(&sfires[t], 1u); atomicAdd(&scnt[nxt], 1u);
            }
            if (!(fired & 4u) && (mem2 * invn - bco > 0.0f)) {
                s2 = 3.0f; fired |= 4u;
                atomicOr(&smask[nxt][wq4 + 2], 1ull << co);
                atomicAdd(&sfires[t], 1u); atomicAdd(&scnt[nxt], 1u);
            }
            if (!(fired & 8u) && (mem3 * invn - bco > 0.0f)) {
                s3 = 3.0f; fired |= 8u;
                atomicOr(&smask[nxt][wq4 + 3], 1ull << co);
                atomicAdd(&sfires[t], 1u); atomicAdd(&scnt[nxt], 1u);
            }

            float4 sv = make_float4(s0, s1, s2, s3);
            *(float4*)(out + (((size_t)(bb * NO + co) * NT + t) * NW + w0 + wq4)) = sv;

            __syncthreads();
        }

        // ---- commit prefetched tile (conv readers of old tile are long done) ----
        if (ch + 1 < NCHUNK) {
#pragma unroll
            for (int k = 0; k < 8; ++k) {
                int i = tid + k * 256;
                if (i < NC * NROWS * 20) ((float*)xsh)[i] = sreg[k];
            }
            __syncthreads();
        }
    }

    atomicAdd(&gfires[tid], sfires[tid]);
}

__global__ __launch_bounds__(256)
void fin_kernel(const unsigned int* __restrict__ gfires, float* __restrict__ out)
{
    const int tid = threadIdx.x;
    unsigned int v = gfires[tid];
    unsigned int s = v, m = v;
    for (int off = 32; off > 0; off >>= 1) {
        s += __shfl_down(s, off);
        unsigned int o = __shfl_down(m, off);
        m = m > o ? m : o;
    }
    __shared__ unsigned int ls[4], lm[4];
    if ((tid & 63) == 0) { ls[tid >> 6] = s; lm[tid >> 6] = m; }
    __syncthreads();
    if (tid == 0) {
        unsigned int ts = 0, tm = 0;
        for (int i = 0; i < 4; ++i) { ts += ls[i]; tm = tm > lm[i] ? tm : lm[i]; }
        out[67108864] = 4.5f * (float)ts / 67108864.0f;   // 0.5*9*F/2^26
        out[67108865] = 3.0f * (float)tm / 262144.0f;     // 3*maxF/(32*64*128)
    }
}

extern "C" void kernel_launch(void* const* d_in, const int* in_sizes, int n_in,
                              void* d_out, int out_size, void* d_ws, size_t ws_size,
                              hipStream_t stream)
{
    const float* x    = (const float*)d_in[0];
    const float* w    = (const float*)d_in[1];
    const float* b    = (const float*)d_in[2];
    const float* beta = (const float*)d_in[3];
    // d_in[4] = sigma: unused in forward

    float* out  = (float*)d_out;
    float* wsf  = (float*)d_ws;
    float* d3   = wsf;                               // 4096 floats
    float* invn = wsf + 4096;                        // 64 floats
    unsigned int* gf = (unsigned int*)(wsf + 4160);  // 256 u32

    prep_kernel<<<1, 1024, 0, stream>>>(w, d3, invn, gf);
    spk_kernel<<<256, 256, 0, stream>>>(x, w, b, beta, d3, invn, out, gf);
    fin_kernel<<<1, 256, 0, stream>>>(gf, out);
}

// Round 5
// 778.002 us; speedup vs baseline: 25.8567x; 1.0582x over previous
//
#include <hip/hip_runtime.h>
#include <cstdint>

// SpikingConv2DLayer fused forward, MI355X (gfx950), fp32 exact-path. v3
// (resubmit — round 4 was GPUAcquisitionTimeout, kernel never ran).
//
// v2 post-mortem (652us spk, VALUBusy 54.6%, Occ 11.7%): ~300us idle from
// 8 barriers/chunk (smask LDS round-trips) + 1 wave/SIMD latency exposure.
// v3: lane=cout remap -> fire mask via __ballot (register, no LDS/barrier);
// 512-thread blocks -> 2 waves/SIMD; fire-at-most-once sparsity -> output
// tile streamed from a 2KB code table during the NEXT chunk's conv (stores
// overlap compute, scan loop has no global stores).
//
// Exact facts (absmax 0.0 in v1/v2): single fire of exactly 3.0 per neuron;
// loss = 4.5*F/2^26; spread = 3*maxF_t/2^18.

#define NB 32
#define NC 8
#define NT 256
#define NW 128
#define NO 64
#define WT 16
#define TC 8
#define NROWS 12
#define NCHUNK (NT / TC)
#define XCOLS 20
#define XTILE (NC * NROWS * XCOLS)   // 1920 floats

__global__ __launch_bounds__(1024)
void prep_kernel(const float* __restrict__ w, float* __restrict__ d3,
                 float* __restrict__ invn, unsigned int* __restrict__ gfires)
{
    __shared__ float wsh[NO * 200];
    const int tid = threadIdx.x;
    for (int i = tid; i < NO * 200; i += 1024) wsh[i] = w[i];
    if (tid < NT) gfires[tid] = 0u;
    __syncthreads();
#pragma unroll
    for (int p = 0; p < 4; ++p) {
        int idx = p * 1024 + tid;
        int o = idx >> 6, e = idx & 63;
        float acc = 0.0f;
        for (int i = 0; i < 200; i += 4) {
            float4 av = *(const float4*)&wsh[o * 200 + i];
            float4 bv = *(const float4*)&wsh[e * 200 + i];
            acc += av.x * bv.x + av.y * bv.y + av.z * bv.z + av.w * bv.w;
        }
        d3[idx] = 3.0f * acc;                       // symmetric, includes spike value 3
        if (o == e) invn[o] = 1.0f / (acc + 1e-8f);
    }
}

__global__ __launch_bounds__(512, 2)
void spk_kernel(const float* __restrict__ x, const float* __restrict__ wglob,
                const float* __restrict__ bias, const float* __restrict__ beta_p,
                const float* __restrict__ d3g, const float* __restrict__ invng,
                float* __restrict__ out, unsigned int* __restrict__ gfires)
{
    __shared__ float wsm[NC * 25 * NO];           // [c][kt][kw][co] 51200 B, lane-stride-1
    __shared__ float d3s[NO * NO];                // [c][co] (symmetric) 16384 B
    __shared__ float xsh[2][NC][NROWS][XCOLS];    // 15360 B double-buffered x tile
    __shared__ unsigned short tf[2][NO][8];       // fire-step codes (tfc0|tfc1<<8) 2048 B
    __shared__ unsigned int sf[NT];               // per-t fire counts 1024 B

    const int tid  = threadIdx.x;
    const int lane = tid & 63;        // = cout in conv+scan
    const int wv   = tid >> 6;        // wave 0..7 owns cols 2wv, 2wv+1
    const int bb   = blockIdx.x >> 3;
    const int w0   = (blockIdx.x & 7) * WT;

    // ---- init LDS ----
    for (int i = tid; i < NC * 25 * NO; i += 512) {
        int co = i & 63; int r = i >> 6;          // r = (c*5+kt)*5+kw
        int kw = r % 5; int r2 = r / 5; int kt = r2 % 5; int c = r2 / 5;
        wsm[i] = wglob[((co * NC + c) * 5 + kt) * 5 + kw];
    }
    for (int i = tid; i < NO * NO; i += 512) d3s[i] = d3g[i];
    for (int i = tid; i < NT; i += 512) sf[i] = 0u;

    const size_t xbbase = (size_t)bb * NC * NT * NW;
#pragma unroll
    for (int k = 0; k < 4; ++k) {                 // stage chunk 0 -> buf 0
        int i = tid + k * 512;
        if (i < XTILE) {
            int c = i / (NROWS * XCOLS); int rem = i - c * (NROWS * XCOLS);
            int row = rem / XCOLS; int col = rem - row * XCOLS;
            int tg = row - 2, wg = w0 + col - 2;
            float v = 0.0f;
            if (tg >= 0 && tg < NT && wg >= 0 && wg < NW)
                v = x[xbbase + ((size_t)c * NT + tg) * NW + wg];
            (&xsh[0][0][0][0])[i] = v;
        }
    }

    const float invn = invng[lane];
    const float bco  = bias[lane];
    const float beta = beta_p[0];
    const float omb  = 1.0f - beta;

    float mem0 = 0.f, mem1 = 0.f;
    unsigned int fired = 0u;
    unsigned long long pm0 = 0ull, pm1 = 0ull;    // prev-step fire masks (my 2 cols)

    const int sq = tid & 3;                       // store-phase w-quad
    const int srow = tid >> 2;                    // store-phase row base (0..127)

    __syncthreads();

#pragma unroll 1
    for (int ch = 0; ch < NCHUNK; ++ch) {
        const int buf = ch & 1;
        const int tbase = ch * TC;

        // ---- (a) prefetch next x tile into registers ----
        float sr0 = 0.f, sr1 = 0.f, sr2 = 0.f, sr3 = 0.f;
        if (ch + 1 < NCHUNK) {
#pragma unroll
            for (int k = 0; k < 4; ++k) {
                int i = tid + k * 512;
                float v = 0.0f;
                if (i < XTILE) {
                    int c = i / (NROWS * XCOLS); int rem = i - c * (NROWS * XCOLS);
                    int row = rem / XCOLS; int col = rem - row * XCOLS;
                    int tg = tbase + 6 + row, wg = w0 + col - 2;   // next tbase-2+row
                    if (tg < NT && wg >= 0 && wg < NW)
                        v = x[xbbase + ((size_t)c * NT + tg) * NW + wg];
                }
                if (k == 0) sr0 = v; else if (k == 1) sr1 = v;
                else if (k == 2) sr2 = v; else sr3 = v;
            }
        }

        // ---- (b) store previous chunk's output tile (overlaps conv) ----
        if (ch > 0) {
            const int pbuf = buf ^ 1;
            const int tprev = tbase - TC;
#pragma unroll
            for (int p = 0; p < 4; ++p) {
                int rowi = p * 128 + srow;
                int co = rowi >> 3, tt = rowi & 7;
                unsigned int codes = *(const unsigned int*)&tf[pbuf][co][sq * 2];
                float4 v;
                v.x = (((codes      ) & 0xffu) == (unsigned)tt) ? 3.0f : 0.0f;
                v.y = (((codes >>  8) & 0xffu) == (unsigned)tt) ? 3.0f : 0.0f;
                v.z = (((codes >> 16) & 0xffu) == (unsigned)tt) ? 3.0f : 0.0f;
                v.w = (((codes >> 24) & 0xffu) == (unsigned)tt) ? 3.0f : 0.0f;
                *(float4*)(out + (((size_t)(bb * NO + co) * NT + tprev + tt) * NW + w0 + sq * 4)) = v;
            }
        }

        // ---- (c) conv: acc[t][2 cols], x slices wave-uniform (broadcast reads) ----
        float acc[TC][2];
#pragma unroll
        for (int t = 0; t < TC; ++t) { acc[t][0] = 0.f; acc[t][1] = 0.f; }

#pragma unroll 1
        for (int c = 0; c < NC; ++c) {
            float2 xr[NROWS][3];
#pragma unroll
            for (int r = 0; r < NROWS; ++r) {
                const float* base = &xsh[buf][c][r][2 * wv];
                xr[r][0] = *(const float2*)(base);
                xr[r][1] = *(const float2*)(base + 2);
                xr[r][2] = *(const float2*)(base + 4);
            }
#pragma unroll
            for (int kt = 0; kt < 5; ++kt) {
                const float* wp = &wsm[((c * 5 + kt) * 5) * 64 + lane];
                float wk0 = wp[0], wk1 = wp[64], wk2 = wp[128], wk3 = wp[192], wk4 = wp[256];
#pragma unroll
                for (int t = 0; t < TC; ++t) {
                    float2 a = xr[t + kt][0], b2 = xr[t + kt][1], c2 = xr[t + kt][2];
                    acc[t][0] += wk0 * a.x + wk1 * a.y + wk2 * b2.x + wk3 * b2.y + wk4 * c2.x;
                    acc[t][1] += wk0 * a.y + wk1 * b2.x + wk2 * b2.y + wk3 * c2.x + wk4 * c2.y;
                }
            }
        }

        // ---- (d) scan: 8 steps, barrier-free (ballot fire masks) ----
        unsigned int tfc0 = 0xffu, tfc1 = 0xffu;
#pragma unroll
        for (int tt = 0; tt < TC; ++tt) {
            float r0 = 0.f, r1 = 0.f;
            if (pm0 | pm1) {
                unsigned long long m = pm0;
                while (m) { int c = __builtin_ctzll(m); m &= m - 1; r0 += d3s[c * 64 + lane]; }
                m = pm1;
                while (m) { int c = __builtin_ctzll(m); m &= m - 1; r1 += d3s[c * 64 + lane]; }
            }
            mem0 = (mem0 - r0) * beta + acc[tt][0] * omb;
            mem1 = (mem1 - r1) * beta + acc[tt][1] * omb;
            bool f0 = !(fired & 1u) && (mem0 * invn - bco > 0.0f);
            bool f1 = !(fired & 2u) && (mem1 * invn - bco > 0.0f);
            pm0 = __ballot(f0);
            pm1 = __ballot(f1);
            if (f0) { fired |= 1u; tfc0 = (unsigned)tt; }
            if (f1) { fired |= 2u; tfc1 = (unsigned)tt; }
            unsigned int cnt = (unsigned)(__popcll(pm0) + __popcll(pm1));
            if (lane == 0 && cnt) atomicAdd(&sf[tbase + tt], cnt);
        }
        tf[buf][lane][wv] = (unsigned short)(tfc0 | (tfc1 << 8));

        // ---- (e) commit prefetched tile into other buffer ----
        if (ch + 1 < NCHUNK) {
            float* dst = &xsh[buf ^ 1][0][0][0];
#pragma unroll
            for (int k = 0; k < 4; ++k) {
                int i = tid + k * 512;
                float v = (k == 0) ? sr0 : (k == 1) ? sr1 : (k == 2) ? sr2 : sr3;
                if (i < XTILE) dst[i] = v;
            }
        }
        __syncthreads();
    }

    // ---- epilogue: store last chunk's tile ----
    {
        const int pbuf = (NCHUNK - 1) & 1;
        const int tprev = NT - TC;
#pragma unroll
        for (int p = 0; p < 4; ++p) {
            int rowi = p * 128 + srow;
            int co = rowi >> 3, tt = rowi & 7;
            unsigned int codes = *(const unsigned int*)&tf[pbuf][co][sq * 2];
            float4 v;
            v.x = (((codes      ) & 0xffu) == (unsigned)tt) ? 3.0f : 0.0f;
            v.y = (((codes >>  8) & 0xffu) == (unsigned)tt) ? 3.0f : 0.0f;
            v.z = (((codes >> 16) & 0xffu) == (unsigned)tt) ? 3.0f : 0.0f;
            v.w = (((codes >> 24) & 0xffu) == (unsigned)tt) ? 3.0f : 0.0f;
            *(float4*)(out + (((size_t)(bb * NO + co) * NT + tprev + tt) * NW + w0 + sq * 4)) = v;
        }
    }

    if (tid < NT) atomicAdd(&gfires[tid], sf[tid]);
}

__global__ __launch_bounds__(256)
void fin_kernel(const unsigned int* __restrict__ gfires, float* __restrict__ out)
{
    const int tid = threadIdx.x;
    unsigned int v = gfires[tid];
    unsigned int s = v, m = v;
    for (int off = 32; off > 0; off >>= 1) {
        s += __shfl_down(s, off);
        unsigned int o = __shfl_down(m, off);
        m = m > o ? m : o;
    }
    __shared__ unsigned int ls[4], lm[4];
    if ((tid & 63) == 0) { ls[tid >> 6] = s; lm[tid >> 6] = m; }
    __syncthreads();
    if (tid == 0) {
        unsigned int ts = 0, tm = 0;
        for (int i = 0; i < 4; ++i) { ts += ls[i]; tm = tm > lm[i] ? tm : lm[i]; }
        out[67108864] = 4.5f * (float)ts / 67108864.0f;   // 0.5*9*F/2^26
        out[67108865] = 3.0f * (float)tm / 262144.0f;     // 3*maxF/(32*64*128)
    }
}

extern "C" void kernel_launch(void* const* d_in, const int* in_sizes, int n_in,
                              void* d_out, int out_size, void* d_ws, size_t ws_size,
                              hipStream_t stream)
{
    const float* x    = (const float*)d_in[0];
    const float* w    = (const float*)d_in[1];
    const float* b    = (const float*)d_in[2];
    const float* beta = (const float*)d_in[3];
    // d_in[4] = sigma: unused in forward

    float* out  = (float*)d_out;
    float* wsf  = (float*)d_ws;
    float* d3   = wsf;                               // 4096 floats
    float* invn = wsf + 4096;                        // 64 floats
    unsigned int* gf = (unsigned int*)(wsf + 4160);  // 256 u32

    prep_kernel<<<1, 1024, 0, stream>>>(w, d3, invn, gf);
    spk_kernel<<<256, 512, 0, stream>>>(x, w, b, beta, d3, invn, out, gf);
    fin_kernel<<<1, 256, 0, stream>>>(gf, out);
}

// Round 6
// 752.772 us; speedup vs baseline: 26.7233x; 1.0335x over previous
//
#include <hip/hip_runtime.h>
#include <cstdint>
#include <math.h>

// SpikingConv2DLayer fused forward, MI355X (gfx950), fp32 exact-path. v4.
//
// v3 post-mortem (spk 585us, VALUBusy 65.4% -> 382us busy vs 171us FMA floor):
// VALU inst count fits 2x-conv (mul+add, no FP contraction) + ~700 overhead.
// v4: explicit fmaf chains in conv (forces v_fma_f32), #pragma unroll 2 on
// c-loop (cross-iter LDS/FMA overlap, launch_bounds(512,1) removes the
// 256-VGPR cliff), and per-thread prefetch/store addressing hoisted out of
// the chunk loop. Structure (ballot scan, code-table store, double-buffered
// x tile) unchanged from v3.
//
// Exact facts (absmax 0.0 in v1/v2/v3): single fire of exactly 3.0 per
// neuron; loss = 4.5*F/2^26; spread = 3*maxF_t/2^18.

#define NB 32
#define NC 8
#define NT 256
#define NW 128
#define NO 64
#define WT 16
#define TC 8
#define NROWS 12
#define NCHUNK (NT / TC)
#define XCOLS 20
#define XTILE (NC * NROWS * XCOLS)   // 1920 floats

__global__ __launch_bounds__(1024)
void prep_kernel(const float* __restrict__ w, float* __restrict__ d3,
                 float* __restrict__ invn, unsigned int* __restrict__ gfires)
{
    __shared__ float wsh[NO * 200];
    const int tid = threadIdx.x;
    for (int i = tid; i < NO * 200; i += 1024) wsh[i] = w[i];
    if (tid < NT) gfires[tid] = 0u;
    __syncthreads();
#pragma unroll
    for (int p = 0; p < 4; ++p) {
        int idx = p * 1024 + tid;
        int o = idx >> 6, e = idx & 63;
        float acc = 0.0f;
        for (int i = 0; i < 200; i += 4) {
            float4 av = *(const float4*)&wsh[o * 200 + i];
            float4 bv = *(const float4*)&wsh[e * 200 + i];
            acc += av.x * bv.x + av.y * bv.y + av.z * bv.z + av.w * bv.w;
        }
        d3[idx] = 3.0f * acc;                       // symmetric, includes spike value 3
        if (o == e) invn[o] = 1.0f / (acc + 1e-8f);
    }
}

__global__ __launch_bounds__(512, 1)
void spk_kernel(const float* __restrict__ x, const float* __restrict__ wglob,
                const float* __restrict__ bias, const float* __restrict__ beta_p,
                const float* __restrict__ d3g, const float* __restrict__ invng,
                float* __restrict__ out, unsigned int* __restrict__ gfires)
{
    __shared__ float wsm[NC * 25 * NO];           // [c][kt][kw][co] 51200 B, lane-stride-1
    __shared__ float d3s[NO * NO];                // [c][co] (symmetric) 16384 B
    __shared__ float xsh[2][NC][NROWS][XCOLS];    // 15360 B double-buffered x tile
    __shared__ unsigned short tf[2][NO][8];       // fire-step codes (tfc0|tfc1<<8) 2048 B
    __shared__ unsigned int sf[NT];               // per-t fire counts 1024 B

    const int tid  = threadIdx.x;
    const int lane = tid & 63;        // = cout in conv+scan
    const int wv   = tid >> 6;        // wave 0..7 owns cols 2wv, 2wv+1
    const int bb   = blockIdx.x >> 3;
    const int w0   = (blockIdx.x & 7) * WT;

    // ---- init LDS ----
    for (int i = tid; i < NC * 25 * NO; i += 512) {
        int co = i & 63; int r = i >> 6;          // r = (c*5+kt)*5+kw
        int kw = r % 5; int r2 = r / 5; int kt = r2 % 5; int c = r2 / 5;
        wsm[i] = wglob[((co * NC + c) * 5 + kt) * 5 + kw];
    }
    for (int i = tid; i < NO * NO; i += 512) d3s[i] = d3g[i];
    for (int i = tid; i < NT; i += 512) sf[i] = 0u;

    const size_t xbbase = (size_t)bb * NC * NT * NW;

    // ---- per-thread static prefetch descriptors (hoisted addressing) ----
    const float* pf_ptr[4];   // &x[tg=6+row] base (chunk 0); advance ch*TC*NW
    int  pf_idx[4];           // linear LDS tile index, or -1
    int  pf_row[4];           // for tg bound: tg = ch*8 + 6 + row
    bool pf_okw[4];           // w-range validity
#pragma unroll
    for (int k = 0; k < 4; ++k) {
        int i = tid + k * 512;
        if (i < XTILE) {
            int c = i / (NROWS * XCOLS); int rem = i - c * (NROWS * XCOLS);
            int row = rem / XCOLS; int col = rem - row * XCOLS;
            int wg = w0 + col - 2;
            pf_idx[k] = i; pf_row[k] = row;
            pf_okw[k] = (wg >= 0 && wg < NW);
            pf_ptr[k] = x + xbbase + ((size_t)c * NT + 6 + row) * NW + (wg < 0 ? 0 : wg);
        } else { pf_idx[k] = -1; pf_row[k] = 0; pf_okw[k] = false; pf_ptr[k] = x; }
    }

    // ---- per-thread static store descriptors ----
    const int sq = tid & 3;                       // store-phase w-quad
    const int srow = tid >> 2;                    // store-phase row base (0..127)
    int    sp_tfidx[4];                           // u16 index within tf[pbuf]
    int    sp_tt[4];
    float* sp_out[4];                             // out base at tprev=0
#pragma unroll
    for (int p = 0; p < 4; ++p) {
        int rowi = p * 128 + srow;
        int co = rowi >> 3, tt = rowi & 7;
        sp_tfidx[p] = co * 8 + sq * 2;
        sp_tt[p] = tt;
        sp_out[p] = out + (((size_t)(bb * NO + co) * NT + tt) * NW + w0 + sq * 4);
    }

    // ---- stage chunk 0 -> buf 0 (rows -2..9) ----
#pragma unroll
    for (int k = 0; k < 4; ++k) {
        int i = tid + k * 512;
        if (i < XTILE) {
            int c = i / (NROWS * XCOLS); int rem = i - c * (NROWS * XCOLS);
            int row = rem / XCOLS; int col = rem - row * XCOLS;
            int tg = row - 2, wg = w0 + col - 2;
            float v = 0.0f;
            if (tg >= 0 && tg < NT && wg >= 0 && wg < NW)
                v = x[xbbase + ((size_t)c * NT + tg) * NW + wg];
            (&xsh[0][0][0][0])[i] = v;
        }
    }

    const float invn = invng[lane];
    const float bco  = bias[lane];
    const float beta = beta_p[0];
    const float omb  = 1.0f - beta;

    float mem0 = 0.f, mem1 = 0.f;
    unsigned int fired = 0u;
    unsigned long long pm0 = 0ull, pm1 = 0ull;    // prev-step fire masks (my 2 cols)

    __syncthreads();

#pragma unroll 1
    for (int ch = 0; ch < NCHUNK; ++ch) {
        const int buf = ch & 1;
        const int tbase = ch * TC;

        // ---- (a) prefetch next x tile into registers ----
        float sr[4];
        if (ch + 1 < NCHUNK) {
#pragma unroll
            for (int k = 0; k < 4; ++k) {
                float v = 0.0f;
                int tg = (ch << 3) + 6 + pf_row[k];
                if (pf_okw[k] && tg < NT)
                    v = pf_ptr[k][(size_t)ch * (TC * NW)];
                sr[k] = v;
            }
        }

        // ---- (b) store previous chunk's output tile (overlaps conv) ----
        if (ch > 0) {
            const unsigned short* tfp = &tf[buf ^ 1][0][0];
            const size_t oadv = (size_t)(ch - 1) * (TC * NW);
#pragma unroll
            for (int p = 0; p < 4; ++p) {
                unsigned int codes = *(const unsigned int*)(tfp + sp_tfidx[p]);
                unsigned int tt = (unsigned)sp_tt[p];
                float4 v;
                v.x = (((codes      ) & 0xffu) == tt) ? 3.0f : 0.0f;
                v.y = (((codes >>  8) & 0xffu) == tt) ? 3.0f : 0.0f;
                v.z = (((codes >> 16) & 0xffu) == tt) ? 3.0f : 0.0f;
                v.w = (((codes >> 24) & 0xffu) == tt) ? 3.0f : 0.0f;
                *(float4*)(sp_out[p] + oadv) = v;
            }
        }

        // ---- (c) conv: acc[t][2 cols], explicit fmaf, unroll-2 c-loop ----
        float acc[TC][2];
#pragma unroll
        for (int t = 0; t < TC; ++t) { acc[t][0] = 0.f; acc[t][1] = 0.f; }

#pragma unroll 2
        for (int c = 0; c < NC; ++c) {
            float2 xr[NROWS][3];
#pragma unroll
            for (int r = 0; r < NROWS; ++r) {
                const float* base = &xsh[buf][c][r][2 * wv];
                xr[r][0] = *(const float2*)(base);
                xr[r][1] = *(const float2*)(base + 2);
                xr[r][2] = *(const float2*)(base + 4);
            }
#pragma unroll
            for (int kt = 0; kt < 5; ++kt) {
                const float* wp = &wsm[((c * 5 + kt) * 5) * 64 + lane];
                float wk0 = wp[0], wk1 = wp[64], wk2 = wp[128], wk3 = wp[192], wk4 = wp[256];
#pragma unroll
                for (int t = 0; t < TC; ++t) {
                    float2 a = xr[t + kt][0], b2 = xr[t + kt][1], c2 = xr[t + kt][2];
                    float u0 = acc[t][0], u1 = acc[t][1];
                    u0 = fmaf(wk0, a.x,  u0);
                    u0 = fmaf(wk1, a.y,  u0);
                    u0 = fmaf(wk2, b2.x, u0);
                    u0 = fmaf(wk3, b2.y, u0);
                    u0 = fmaf(wk4, c2.x, u0);
                    u1 = fmaf(wk0, a.y,  u1);
                    u1 = fmaf(wk1, b2.x, u1);
                    u1 = fmaf(wk2, b2.y, u1);
                    u1 = fmaf(wk3, c2.x, u1);
                    u1 = fmaf(wk4, c2.y, u1);
                    acc[t][0] = u0; acc[t][1] = u1;
                }
            }
        }

        // ---- (d) scan: 8 steps, barrier-free (ballot fire masks) ----
        unsigned int tfc0 = 0xffu, tfc1 = 0xffu;
#pragma unroll
        for (int tt = 0; tt < TC; ++tt) {
            float r0 = 0.f, r1 = 0.f;
            if (pm0 | pm1) {
                unsigned long long m = pm0;
                while (m) { int c = __builtin_ctzll(m); m &= m - 1; r0 += d3s[c * 64 + lane]; }
                m = pm1;
                while (m) { int c = __builtin_ctzll(m); m &= m - 1; r1 += d3s[c * 64 + lane]; }
            }
            mem0 = (mem0 - r0) * beta + acc[tt][0] * omb;
            mem1 = (mem1 - r1) * beta + acc[tt][1] * omb;
            bool f0 = !(fired & 1u) && (mem0 * invn - bco > 0.0f);
            bool f1 = !(fired & 2u) && (mem1 * invn - bco > 0.0f);
            pm0 = __ballot(f0);
            pm1 = __ballot(f1);
            if (f0) { fired |= 1u; tfc0 = (unsigned)tt; }
            if (f1) { fired |= 2u; tfc1 = (unsigned)tt; }
            unsigned int cnt = (unsigned)(__popcll(pm0) + __popcll(pm1));
            if (lane == 0 && cnt) atomicAdd(&sf[tbase + tt], cnt);
        }
        tf[buf][lane][wv] = (unsigned short)(tfc0 | (tfc1 << 8));

        // ---- (e) commit prefetched tile into other buffer ----
        if (ch + 1 < NCHUNK) {
            float* dst = &xsh[buf ^ 1][0][0][0];
#pragma unroll
            for (int k = 0; k < 4; ++k) {
                if (pf_idx[k] >= 0) dst[pf_idx[k]] = sr[k];
            }
        }
        __syncthreads();
    }

    // ---- epilogue: store last chunk's tile ----
    {
        const unsigned short* tfp = &tf[(NCHUNK - 1) & 1][0][0];
        const size_t oadv = (size_t)(NCHUNK - 1) * (TC * NW);
#pragma unroll
        for (int p = 0; p < 4; ++p) {
            unsigned int codes = *(const unsigned int*)(tfp + sp_tfidx[p]);
            unsigned int tt = (unsigned)sp_tt[p];
            float4 v;
            v.x = (((codes      ) & 0xffu) == tt) ? 3.0f : 0.0f;
            v.y = (((codes >>  8) & 0xffu) == tt) ? 3.0f : 0.0f;
            v.z = (((codes >> 16) & 0xffu) == tt) ? 3.0f : 0.0f;
            v.w = (((codes >> 24) & 0xffu) == tt) ? 3.0f : 0.0f;
            *(float4*)(sp_out[p] + oadv) = v;
        }
    }

    if (tid < NT) atomicAdd(&gfires[tid], sf[tid]);
}

__global__ __launch_bounds__(256)
void fin_kernel(const unsigned int* __restrict__ gfires, float* __restrict__ out)
{
    const int tid = threadIdx.x;
    unsigned int v = gfires[tid];
    unsigned int s = v, m = v;
    for (int off = 32; off > 0; off >>= 1) {
        s += __shfl_down(s, off);
        unsigned int o = __shfl_down(m, off);
        m = m > o ? m : o;
    }
    __shared__ unsigned int ls[4], lm[4];
    if ((tid & 63) == 0) { ls[tid >> 6] = s; lm[tid >> 6] = m; }
    __syncthreads();
    if (tid == 0) {
        unsigned int ts = 0, tm = 0;
        for (int i = 0; i < 4; ++i) { ts += ls[i]; tm = tm > lm[i] ? tm : lm[i]; }
        out[67108864] = 4.5f * (float)ts / 67108864.0f;   // 0.5*9*F/2^26
        out[67108865] = 3.0f * (float)tm / 262144.0f;     // 3*maxF/(32*64*128)
    }
}

extern "C" void kernel_launch(void* const* d_in, const int* in_sizes, int n_in,
                              void* d_out, int out_size, void* d_ws, size_t ws_size,
                              hipStream_t stream)
{
    const float* x    = (const float*)d_in[0];
    const float* w    = (const float*)d_in[1];
    const float* b    = (const float*)d_in[2];
    const float* beta = (const float*)d_in[3];
    // d_in[4] = sigma: unused in forward

    float* out  = (float*)d_out;
    float* wsf  = (float*)d_ws;
    float* d3   = wsf;                               // 4096 floats
    float* invn = wsf + 4096;                        // 64 floats
    unsigned int* gf = (unsigned int*)(wsf + 4160);  // 256 u32

    prep_kernel<<<1, 1024, 0, stream>>>(w, d3, invn, gf);
    spk_kernel<<<256, 512, 0, stream>>>(x, w, b, beta, d3, invn, out, gf);
    fin_kernel<<<1, 256, 0, stream>>>(gf, out);
}